// Round 4
// baseline (625.113 us; speedup 1.0000x reference)
//
#include <hip/hip_runtime.h>
#include <hip/hip_bf16.h>
#include <math.h>

#define S_LEN 2048
#define D_MODEL 1024
#define N_BATCH 4
#define N_HALF 512

typedef unsigned short u16;
typedef __attribute__((ext_vector_type(8))) short bf16x8;
typedef __attribute__((ext_vector_type(4))) float f32x4;

// ---------- helpers ----------
__device__ inline u16 f2bf(float v) {
  __hip_bfloat16 h = __float2bfloat16(v);   // RNE
  return *reinterpret_cast<u16*>(&h);
}
__device__ inline float bf2f(u16 u) {
  __hip_bfloat16 h = *reinterpret_cast<__hip_bfloat16*>(&u);
  return __bfloat162float(h);
}
// async global->LDS, 16B per lane; LDS dest is wave-uniform base + lane*16
__device__ inline void gl2lds16(const void* g, void* l) {
  __builtin_amdgcn_global_load_lds(
      (const __attribute__((address_space(1))) unsigned int*)g,
      (__attribute__((address_space(3))) unsigned int*)l, 16, 0, 0);
}
// tanh via v_exp_f32; exact at 0, saturates correctly at +/-inf (no NaN)
__device__ inline float fast_tanh(float x) {
  float e = __expf(2.0f * x);
  return 1.0f - 2.0f / (e + 1.0f);
}

// ---------- casts ----------
__global__ __launch_bounds__(256)
void cast_bf(const float* __restrict__ src, u16* __restrict__ dst, long long n) {
  long long i = (long long)blockIdx.x * 256 + threadIdx.x;
  if (i < n) dst[i] = f2bf(src[i]);
}
__global__ __launch_bounds__(256)
void cast_split(const float* __restrict__ src, u16* __restrict__ hi,
                u16* __restrict__ lo, long long n) {
  long long i = (long long)blockIdx.x * 256 + threadIdx.x;
  if (i < n) {
    float v = src[i];
    u16 h = f2bf(v);
    hi[i] = h;
    lo[i] = f2bf(v - bf2f(h));
  }
}
__global__ __launch_bounds__(256)
void zero_stats(float* __restrict__ p, int n) {
  int i = blockIdx.x * 256 + threadIdx.x;
  if (i < n) p[i] = 0.f;
}

// ============================================================
// Core MFMA GEMM (NT): C[M,N] = A[M,K] * B[N,K]^T, bf16 in, fp32 acc.
// 128x128 tile, 256 thr (4 waves, 2x2 of 64x64), BK=32,
// global_load_lds width16, LDS row-major [128][32].
// EPI: 0 = bf16 out + bias[col]     (Q, K, pf)
//      1 = bf16 out + bias[row]     (Vt)
//      2 = hi/lo bf16 out, no bias  (av)
// ============================================================
template<int EPI>
__global__ __launch_bounds__(256)
void mfma_gemm(const u16* __restrict__ A, const u16* __restrict__ B,
               const float* __restrict__ bias,
               void* __restrict__ C0v, void* __restrict__ C1v,
               int N, int K,
               long long sA, long long sB, long long sC) {
  __shared__ u16 As[128 * 32];
  __shared__ u16 Bs[128 * 32];
  const int tid  = threadIdx.x;
  const int wave = tid >> 6;
  const int lane = tid & 63;
  const int quad = lane >> 4;
  const int tc   = lane & 15;
  const int bm = blockIdx.y * 128;
  const int bn = blockIdx.x * 128;
  const long long z = blockIdx.z;

  const int wm = (wave & 1) * 64;
  const int wn = (wave >> 1) * 64;

  f32x4 acc[4][4];
#pragma unroll
  for (int i = 0; i < 4; i++)
#pragma unroll
    for (int j = 0; j < 4; j++) acc[i][j] = (f32x4){0.f, 0.f, 0.f, 0.f};

  const int srow = wave * 32 + (lane >> 2);
  const int scol = (lane & 3) * 8;
  const u16* ga = A + z * sA + (long long)(bm + srow) * K + scol;
  const u16* gb = B + z * sB + (long long)(bn + srow) * K + scol;
  u16* lA0 = As + (wave * 32) * 32;
  u16* lB0 = Bs + (wave * 32) * 32;
  const long long r16K = 16LL * K;

  for (int k0 = 0; k0 < K; k0 += 32) {
    gl2lds16(ga,        lA0);
    gl2lds16(ga + r16K, lA0 + 512);
    gl2lds16(gb,        lB0);
    gl2lds16(gb + r16K, lB0 + 512);
    ga += 32; gb += 32;
    __syncthreads();
    bf16x8 af[4], bg[4];
#pragma unroll
    for (int i = 0; i < 4; i++)
      af[i] = *(const bf16x8*)(As + (wm + i * 16 + tc) * 32 + quad * 8);
#pragma unroll
    for (int j = 0; j < 4; j++)
      bg[j] = *(const bf16x8*)(Bs + (wn + j * 16 + tc) * 32 + quad * 8);
#pragma unroll
    for (int i = 0; i < 4; i++)
#pragma unroll
      for (int j = 0; j < 4; j++)
        acc[i][j] = __builtin_amdgcn_mfma_f32_16x16x32_bf16(af[i], bg[j], acc[i][j], 0, 0, 0);
    __syncthreads();
  }

#pragma unroll
  for (int i = 0; i < 4; i++) {
    const int row0 = bm + wm + i * 16 + quad * 4;
#pragma unroll
    for (int j = 0; j < 4; j++) {
      const int col = bn + wn + j * 16 + tc;
#pragma unroll
      for (int r = 0; r < 4; r++) {
        float v = acc[i][j][r];
        long long idx = (long long)(row0 + r) * N + col;
        if (EPI == 0) {
          u16* C = (u16*)C0v + z * sC;
          C[idx] = f2bf(v + bias[col]);
        } else if (EPI == 1) {
          u16* C = (u16*)C0v + z * sC;
          C[idx] = f2bf(v + bias[row0 + r]);
        } else if (EPI == 2) {
          u16* Ch = (u16*)C0v + z * sC;
          u16* Cl = (u16*)C1v + z * sC;
          u16 h = f2bf(v);
          Ch[idx] = h;
          Cl[idx] = f2bf(v - bf2f(h));
        }
      }
    }
  }
}

// ============================================================
// Fused chaotic kernel: one K-loop, dual accumulators.
//   acc1 = Q.K^T tile, acc2 = Uq.Uk^T tile
//   chaotic = sc + pc*sy + bif*t*(1-t), sc=acc1/32, sy=acc2/512, t=tanh(sc)
// Writes fp32 Cc once; per-row sync stats via shfl + atomics.
// ============================================================
__global__ __launch_bounds__(256)
void chaotic_fused(const u16* __restrict__ Q, const u16* __restrict__ Kt,
                   const u16* __restrict__ Uq, const u16* __restrict__ Uk,
                   float* __restrict__ Cc,
                   float* __restrict__ ssum, float* __restrict__ ssq,
                   const float* __restrict__ bifp, const float* __restrict__ pcp) {
  __shared__ u16 Qs[128 * 32];
  __shared__ u16 Ks[128 * 32];
  __shared__ u16 Us[128 * 32];
  __shared__ u16 Ws[128 * 32];
  const int tid  = threadIdx.x;
  const int wave = tid >> 6;
  const int lane = tid & 63;
  const int quad = lane >> 4;
  const int tc   = lane & 15;
  const int bm = blockIdx.y * 128;
  const int bn = blockIdx.x * 128;
  const long long z = blockIdx.z;
  const long long sQ = (long long)S_LEN * D_MODEL;
  const int wm = (wave & 1) * 64;
  const int wn = (wave >> 1) * 64;

  f32x4 acc1[4][4], acc2[4][4];
#pragma unroll
  for (int i = 0; i < 4; i++)
#pragma unroll
    for (int j = 0; j < 4; j++) {
      acc1[i][j] = (f32x4){0.f, 0.f, 0.f, 0.f};
      acc2[i][j] = (f32x4){0.f, 0.f, 0.f, 0.f};
    }

  const int srow = wave * 32 + (lane >> 2);
  const int scol = (lane & 3) * 8;
  const long long aoff = (long long)(bm + srow) * D_MODEL + scol;
  const long long boff = (long long)(bn + srow) * D_MODEL + scol;
  const u16* gq = Q  + z * sQ + aoff;
  const u16* gk = Kt + z * sQ + boff;
  const u16* gu = Uq + z * sQ + aoff;
  const u16* gw = Uk + z * sQ + boff;
  const int wb = (wave * 32) * 32;
  const long long r16 = 16LL * D_MODEL;

  for (int k0 = 0; k0 < D_MODEL; k0 += 32) {
    gl2lds16(gq,       Qs + wb);
    gl2lds16(gq + r16, Qs + wb + 512);
    gl2lds16(gk,       Ks + wb);
    gl2lds16(gk + r16, Ks + wb + 512);
    gl2lds16(gu,       Us + wb);
    gl2lds16(gu + r16, Us + wb + 512);
    gl2lds16(gw,       Ws + wb);
    gl2lds16(gw + r16, Ws + wb + 512);
    gq += 32; gk += 32; gu += 32; gw += 32;
    __syncthreads();
    {
      bf16x8 af[4], bg[4];
#pragma unroll
      for (int i = 0; i < 4; i++)
        af[i] = *(const bf16x8*)(Qs + (wm + i * 16 + tc) * 32 + quad * 8);
#pragma unroll
      for (int j = 0; j < 4; j++)
        bg[j] = *(const bf16x8*)(Ks + (wn + j * 16 + tc) * 32 + quad * 8);
#pragma unroll
      for (int i = 0; i < 4; i++)
#pragma unroll
        for (int j = 0; j < 4; j++)
          acc1[i][j] = __builtin_amdgcn_mfma_f32_16x16x32_bf16(af[i], bg[j], acc1[i][j], 0, 0, 0);
    }
    {
      bf16x8 cf[4], dg[4];
#pragma unroll
      for (int i = 0; i < 4; i++)
        cf[i] = *(const bf16x8*)(Us + (wm + i * 16 + tc) * 32 + quad * 8);
#pragma unroll
      for (int j = 0; j < 4; j++)
        dg[j] = *(const bf16x8*)(Ws + (wn + j * 16 + tc) * 32 + quad * 8);
#pragma unroll
      for (int i = 0; i < 4; i++)
#pragma unroll
        for (int j = 0; j < 4; j++)
          acc2[i][j] = __builtin_amdgcn_mfma_f32_16x16x32_bf16(cf[i], dg[j], acc2[i][j], 0, 0, 0);
    }
    __syncthreads();
  }

  const float bif = *bifp;
  const float pc  = *pcp;
  float rsum[4][4], rsq[4][4];
#pragma unroll
  for (int i = 0; i < 4; i++)
#pragma unroll
    for (int r = 0; r < 4; r++) { rsum[i][r] = 0.f; rsq[i][r] = 0.f; }

  float* C = Cc + z * (long long)S_LEN * S_LEN;
#pragma unroll
  for (int i = 0; i < 4; i++) {
    const int row0 = bm + wm + i * 16 + quad * 4;
#pragma unroll
    for (int j = 0; j < 4; j++) {
      const int col = bn + wn + j * 16 + tc;
#pragma unroll
      for (int r = 0; r < 4; r++) {
        float sc = acc1[i][j][r] * 0.03125f;          // / sqrt(1024)
        float sy = acc2[i][j][r] * (1.0f / 512.0f);   // / HALF
        float t  = fast_tanh(sc);
        C[(long long)(row0 + r) * S_LEN + col] = sc + pc * sy + bif * t * (1.0f - t);
        rsum[i][r] += sy;
        rsq[i][r]  += sy * sy;
      }
    }
  }
  // reduce over the 16 lanes (cols) of each quad, then 1 atomic per row
#pragma unroll
  for (int m = 1; m < 16; m <<= 1) {
#pragma unroll
    for (int i = 0; i < 4; i++)
#pragma unroll
      for (int r = 0; r < 4; r++) {
        rsum[i][r] += __shfl_xor(rsum[i][r], m);
        rsq[i][r]  += __shfl_xor(rsq[i][r], m);
      }
  }
  if (tc == 0) {
#pragma unroll
    for (int i = 0; i < 4; i++)
#pragma unroll
      for (int r = 0; r < 4; r++) {
        long long rr = z * S_LEN + bm + wm + i * 16 + quad * 4 + r;
        atomicAdd(&ssum[rr], rsum[i][r]);
        atomicAdd(&ssq[rr],  rsq[i][r]);
      }
  }
}

// ============================================================
// Split-precision output GEMM: out = (Ah+Al)(Bh+Bl)^T + bias, fp32 out.
// 3 MFMAs per frag step (drop Al*Bl). Same tile structure.
// ============================================================
__global__ __launch_bounds__(256)
void mfma_gemm_out3(const u16* __restrict__ Ah, const u16* __restrict__ Al,
                    const u16* __restrict__ Bh, const u16* __restrict__ Bl,
                    const float* __restrict__ bias, float* __restrict__ C,
                    int N, int K) {
  __shared__ u16 Ash[128 * 32];
  __shared__ u16 Asl[128 * 32];
  __shared__ u16 Bsh[128 * 32];
  __shared__ u16 Bsl[128 * 32];
  const int tid  = threadIdx.x;
  const int wave = tid >> 6;
  const int lane = tid & 63;
  const int quad = lane >> 4;
  const int tc   = lane & 15;
  const int bm = blockIdx.y * 128;
  const int bn = blockIdx.x * 128;
  const int wm = (wave & 1) * 64;
  const int wn = (wave >> 1) * 64;

  f32x4 acc[4][4];
#pragma unroll
  for (int i = 0; i < 4; i++)
#pragma unroll
    for (int j = 0; j < 4; j++) acc[i][j] = (f32x4){0.f, 0.f, 0.f, 0.f};

  const int srow = wave * 32 + (lane >> 2);
  const int scol = (lane & 3) * 8;
  long long aoff = (long long)(bm + srow) * K + scol;
  long long boff = (long long)(bn + srow) * K + scol;
  const u16 *gah = Ah + aoff, *gal = Al + aoff;
  const u16 *gbh = Bh + boff, *gbl = Bl + boff;
  const int wbase = (wave * 32) * 32;
  const long long r16K = 16LL * K;

  for (int k0 = 0; k0 < K; k0 += 32) {
    gl2lds16(gah,        Ash + wbase);
    gl2lds16(gah + r16K, Ash + wbase + 512);
    gl2lds16(gal,        Asl + wbase);
    gl2lds16(gal + r16K, Asl + wbase + 512);
    gl2lds16(gbh,        Bsh + wbase);
    gl2lds16(gbh + r16K, Bsh + wbase + 512);
    gl2lds16(gbl,        Bsl + wbase);
    gl2lds16(gbl + r16K, Bsl + wbase + 512);
    gah += 32; gal += 32; gbh += 32; gbl += 32;
    __syncthreads();
    bf16x8 ah[4], al[4], bh[4], bl[4];
#pragma unroll
    for (int i = 0; i < 4; i++) {
      int o = (wm + i * 16 + tc) * 32 + quad * 8;
      ah[i] = *(const bf16x8*)(Ash + o);
      al[i] = *(const bf16x8*)(Asl + o);
    }
#pragma unroll
    for (int j = 0; j < 4; j++) {
      int o = (wn + j * 16 + tc) * 32 + quad * 8;
      bh[j] = *(const bf16x8*)(Bsh + o);
      bl[j] = *(const bf16x8*)(Bsl + o);
    }
#pragma unroll
    for (int i = 0; i < 4; i++)
#pragma unroll
      for (int j = 0; j < 4; j++) {
        acc[i][j] = __builtin_amdgcn_mfma_f32_16x16x32_bf16(ah[i], bh[j], acc[i][j], 0, 0, 0);
        acc[i][j] = __builtin_amdgcn_mfma_f32_16x16x32_bf16(ah[i], bl[j], acc[i][j], 0, 0, 0);
        acc[i][j] = __builtin_amdgcn_mfma_f32_16x16x32_bf16(al[i], bh[j], acc[i][j], 0, 0, 0);
      }
    __syncthreads();
  }
#pragma unroll
  for (int i = 0; i < 4; i++) {
    const int row0 = bm + wm + i * 16 + quad * 4;
#pragma unroll
    for (int j = 0; j < 4; j++) {
      const int col = bn + wn + j * 16 + tc;
#pragma unroll
      for (int r = 0; r < 4; r++)
        C[(long long)(row0 + r) * N + col] = acc[i][j][r] + bias[col];
    }
  }
}

// ============================================================
// Phase normalize in place on bf16 pf rows: [re|im] -> [re/r | im/r]
// ============================================================
__global__ __launch_bounds__(256)
void phase_norm_bf(u16* __restrict__ U, long long n_rows) {
  long long idx = (long long)blockIdx.x * 256 + threadIdx.x;
  if (idx >= n_rows * N_HALF) return;
  long long row = idx >> 9;
  int j = (int)(idx & (N_HALF - 1));
  u16* p = U + row * D_MODEL;
  float re = bf2f(p[j]), im = bf2f(p[j + N_HALF]);
  float n2 = re * re + im * im;
  float cr = 1.f, sr = 0.f;
  if (n2 > 0.f) {
    float inv = 1.0f / sqrtf(n2);
    cr = re * inv; sr = im * inv;
  }
  p[j] = f2bf(cr); p[j + N_HALF] = f2bf(sr);
}

// ============================================================
// Row softmax: fp32 in (chaotic), bf16 out (attn). 1 block / row.
// ============================================================
__global__ __launch_bounds__(256)
void softmax_bf(const float* __restrict__ Cc, u16* __restrict__ P) {
  const long long row = (long long)blockIdx.y * S_LEN + blockIdx.x;
  const float* p = Cc + row * S_LEN;
  u16* q = P + row * S_LEN;
  const int tid = threadIdx.x;
  float v[8];
  float m = -3.402823466e+38f;
#pragma unroll
  for (int i = 0; i < 8; i++) { v[i] = p[tid + i * 256]; m = fmaxf(m, v[i]); }
#pragma unroll
  for (int mask = 1; mask < 64; mask <<= 1) m = fmaxf(m, __shfl_xor(m, mask));
  __shared__ float red[8];
  if ((tid & 63) == 0) red[tid >> 6] = m;
  __syncthreads();
  m = fmaxf(fmaxf(red[0], red[1]), fmaxf(red[2], red[3]));
  float s = 0.f;
#pragma unroll
  for (int i = 0; i < 8; i++) { v[i] = __expf(v[i] - m); s += v[i]; }
#pragma unroll
  for (int mask = 1; mask < 64; mask <<= 1) s += __shfl_xor(s, mask);
  __syncthreads();
  if ((tid & 63) == 0) red[4 + (tid >> 6)] = s;
  __syncthreads();
  s = red[4] + red[5] + red[6] + red[7];
  float inv = 1.0f / s;
#pragma unroll
  for (int i = 0; i < 8; i++) q[tid + i * 256] = f2bf(v[i] * inv);
}

// ============================================================
// sync_loss
// ============================================================
__global__ __launch_bounds__(1024)
void syncloss_kernel(const float* __restrict__ ssum, const float* __restrict__ ssq,
                     float* __restrict__ out) {
  const int tid = threadIdx.x;
  float acc = 0.f;
  for (int r = tid; r < N_BATCH * S_LEN; r += 1024) {
    float su = ssum[r], sq = ssq[r];
    acc += (sq - su * su * (1.0f / 2048.0f)) * (1.0f / 2047.0f);
  }
#pragma unroll
  for (int mask = 1; mask < 64; mask <<= 1) acc += __shfl_xor(acc, mask);
  __shared__ float red[16];
  if ((tid & 63) == 0) red[tid >> 6] = acc;
  __syncthreads();
  if (tid == 0) {
    float t = 0.f;
#pragma unroll
    for (int k = 0; k < 16; k++) t += red[k];
    out[0] = 0.01f * (t / (float)(N_BATCH * S_LEN));
  }
}

extern "C" void kernel_launch(void* const* d_in, const int* in_sizes, int n_in,
                              void* d_out, int out_size, void* d_ws, size_t ws_size,
                              hipStream_t stream) {
  const float* x    = (const float*)d_in[0];
  const float* Wq   = (const float*)d_in[1];
  const float* bq   = (const float*)d_in[2];
  const float* Wk   = (const float*)d_in[3];
  const float* bk   = (const float*)d_in[4];
  const float* Wv   = (const float*)d_in[5];
  const float* bv   = (const float*)d_in[6];
  const float* Wp   = (const float*)d_in[7];
  const float* bp   = (const float*)d_in[8];
  const float* Wo   = (const float*)d_in[9];
  const float* bo   = (const float*)d_in[10];
  const float* bifp = (const float*)d_in[11];
  const float* pcp  = (const float*)d_in[12];
  float* out = (float*)d_out;

  const long long NROW = (long long)N_BATCH * S_LEN;   // 8192
  const long long TD   = NROW * D_MODEL;               // 8,388,608
  const long long WSZ  = (long long)D_MODEL * D_MODEL; // 1,048,576

  // workspace layout (~180 MB)
  u16* xbf = (u16*)d_ws;            // TD
  u16* wqb = xbf + TD;              // WSZ each
  u16* wkb = wqb + WSZ;
  u16* wvb = wkb + WSZ;
  u16* wpb = wvb + WSZ;
  u16* woh = wpb + WSZ;
  u16* wol = woh + WSZ;
  u16* Qbf = wol + WSZ;             // TD
  u16* Kbf = Qbf + TD;              // TD (contiguous with Qbf)
  u16* pfQ = Kbf + TD;              // TD  (-> Uq, later av_hi)
  u16* pfK = pfQ + TD;              // TD  (-> Uk, later av_lo; contiguous with pfQ)
  u16* Vt  = pfK + TD;              // TD  ([b][d][s])
  float* Cc = (float*)(Vt + TD);    // B*S*S fp32
  float* ssum = Cc + (long long)N_BATCH * S_LEN * S_LEN;
  float* ssq  = ssum + NROW;
  u16* attn = Qbf;                  // overlays Q+K after chaotic
  u16* avh = pfQ;                   // overlays Uq after av
  u16* avl = pfK;

  dim3 blk(256);
  const long long sQ = (long long)S_LEN * D_MODEL;   // 2048*1024
  const long long sS = (long long)S_LEN * S_LEN;     // 2048*2048

  // casts
  cast_bf<<<(int)(TD / 256), blk, 0, stream>>>(x, xbf, TD);
  cast_bf<<<(int)(WSZ / 256), blk, 0, stream>>>(Wq, wqb, WSZ);
  cast_bf<<<(int)(WSZ / 256), blk, 0, stream>>>(Wk, wkb, WSZ);
  cast_bf<<<(int)(WSZ / 256), blk, 0, stream>>>(Wv, wvb, WSZ);
  cast_bf<<<(int)(WSZ / 256), blk, 0, stream>>>(Wp, wpb, WSZ);
  cast_split<<<(int)(WSZ / 256), blk, 0, stream>>>(Wo, woh, wol, WSZ);

  // Q = x@Wq^T+bq, K = x@Wk^T+bk   (bf16 out)
  mfma_gemm<0><<<dim3(8, 64, 1), blk, 0, stream>>>(xbf, wqb, bq, Qbf, nullptr,
      D_MODEL, D_MODEL, 0, 0, 0);
  mfma_gemm<0><<<dim3(8, 64, 1), blk, 0, stream>>>(xbf, wkb, bk, Kbf, nullptr,
      D_MODEL, D_MODEL, 0, 0, 0);
  // Vt[b][d][s] = Wv@x_b^T + bv[d]  (row bias, bf16 out)
  mfma_gemm<1><<<dim3(16, 8, N_BATCH), blk, 0, stream>>>(wvb, xbf, bv, Vt, nullptr,
      S_LEN, D_MODEL, 0, sQ, (long long)D_MODEL * S_LEN);
  // pf = [Q;K]@Wp^T + bp  (single launch over 16384 contiguous rows)
  mfma_gemm<0><<<dim3(8, 128, 1), blk, 0, stream>>>(Qbf, wpb, bp, pfQ, nullptr,
      D_MODEL, D_MODEL, 0, 0, 0);
  phase_norm_bf<<<(int)(2 * NROW * N_HALF / 256), blk, 0, stream>>>(pfQ, 2 * NROW);
  zero_stats<<<(int)((2 * NROW + 255) / 256), blk, 0, stream>>>(ssum, (int)(2 * NROW));

  // fused: scores + sync + chaotic -> Cc (fp32), + row stats
  chaotic_fused<<<dim3(16, 16, N_BATCH), blk, 0, stream>>>(
      Qbf, Kbf, pfQ, pfK, Cc, ssum, ssq, bifp, pcp);
  // softmax (fp32 in, bf16 attn out; overlays Q/K)
  softmax_bf<<<dim3(S_LEN, N_BATCH), blk, 0, stream>>>(Cc, attn);
  // av = attn @ Vt^T  -> hi/lo bf16 (overlays Uq/Uk)
  mfma_gemm<2><<<dim3(8, 16, N_BATCH), blk, 0, stream>>>(attn, Vt, nullptr, avh, avl,
      D_MODEL, S_LEN, sS, (long long)D_MODEL * S_LEN, sQ);
  // out = (avh+avl)@(Woh+Wol)^T + bo   (fp32, split 3-MFMA)
  mfma_gemm_out3<<<dim3(8, 64, 1), blk, 0, stream>>>(avh, avl, woh, wol, bo, out,
      D_MODEL, D_MODEL);
  // sync_loss
  syncloss_kernel<<<1, 1024, 0, stream>>>(ssum, ssq, out + TD);
}

// Round 6
// 554.854 us; speedup vs baseline: 1.1266x; 1.1266x over previous
//
#include <hip/hip_runtime.h>
#include <hip/hip_bf16.h>
#include <math.h>

#define S_LEN 2048
#define D_MODEL 1024
#define N_BATCH 4
#define N_HALF 512

typedef unsigned short u16;
typedef __attribute__((ext_vector_type(8))) short bf16x8;
typedef __attribute__((ext_vector_type(4))) float f32x4;

// ---------- helpers ----------
__device__ inline u16 f2bf(float v) {
  __hip_bfloat16 h = __float2bfloat16(v);   // RNE
  return *reinterpret_cast<u16*>(&h);
}
__device__ inline float bf2f(u16 u) {
  __hip_bfloat16 h = *reinterpret_cast<__hip_bfloat16*>(&u);
  return __bfloat162float(h);
}
// async global->LDS, 16B per lane; LDS dest is wave-uniform base + lane*16
__device__ inline void gl2lds16(const void* g, void* l) {
  __builtin_amdgcn_global_load_lds(
      (const __attribute__((address_space(1))) unsigned int*)g,
      (__attribute__((address_space(3))) unsigned int*)l, 16, 0, 0);
}
// tanh via v_exp_f32; exact at 0, saturates correctly at +/-inf (no NaN)
__device__ inline float fast_tanh(float x) {
  float e = __expf(2.0f * x);
  return 1.0f - 2.0f / (e + 1.0f);
}

// ---------- casts ----------
__global__ __launch_bounds__(256)
void cast_bf(const float* __restrict__ src, u16* __restrict__ dst, long long n) {
  long long i = (long long)blockIdx.x * 256 + threadIdx.x;
  if (i < n) dst[i] = f2bf(src[i]);
}
__global__ __launch_bounds__(256)
void cast_split(const float* __restrict__ src, u16* __restrict__ hi,
                u16* __restrict__ lo, long long n) {
  long long i = (long long)blockIdx.x * 256 + threadIdx.x;
  if (i < n) {
    float v = src[i];
    u16 h = f2bf(v);
    hi[i] = h;
    lo[i] = f2bf(v - bf2f(h));
  }
}
__global__ __launch_bounds__(256)
void zero_stats(float* __restrict__ p, int n) {
  int i = blockIdx.x * 256 + threadIdx.x;
  if (i < n) p[i] = 0.f;
}

// ============================================================
// Core MFMA GEMM (NT): C[M,N] = A[M,K] * B[N,K]^T, bf16 in, fp32 acc.
// 128x128 tile, 256 thr (4 waves, 2x2 of 64x64), BK=32,
// global_load_lds width16, LDS row-major [128][32]. Dense operands (ld = K).
// EPI: 0 = bf16 out + bias[col]  (bias1 selects by z if non-null)
//      1 = bf16 out + bias[row]
//      2 = hi/lo bf16 out, no bias
// ============================================================
template<int EPI>
__global__ __launch_bounds__(256)
void mfma_gemm(const u16* __restrict__ A, const u16* __restrict__ B,
               const float* __restrict__ bias0, const float* __restrict__ bias1,
               void* __restrict__ C0v, void* __restrict__ C1v,
               int N, int K,
               long long sA, long long sB, long long sC) {
  __shared__ u16 As[128 * 32];
  __shared__ u16 Bs[128 * 32];
  const int tid  = threadIdx.x;
  const int wave = tid >> 6;
  const int lane = tid & 63;
  const int quad = lane >> 4;
  const int tc   = lane & 15;
  const int bm = blockIdx.y * 128;
  const int bn = blockIdx.x * 128;
  const long long z = blockIdx.z;
  const float* bias = (bias1 && z) ? bias1 : bias0;

  const int wm = (wave & 1) * 64;
  const int wn = (wave >> 1) * 64;

  f32x4 acc[4][4];
#pragma unroll
  for (int i = 0; i < 4; i++)
#pragma unroll
    for (int j = 0; j < 4; j++) acc[i][j] = (f32x4){0.f, 0.f, 0.f, 0.f};

  const int srow = wave * 32 + (lane >> 2);
  const int scol = (lane & 3) * 8;
  const u16* ga = A + z * sA + (long long)(bm + srow) * K + scol;
  const u16* gb = B + z * sB + (long long)(bn + srow) * K + scol;
  u16* lA0 = As + (wave * 32) * 32;
  u16* lB0 = Bs + (wave * 32) * 32;
  const long long r16K = 16LL * K;

  for (int k0 = 0; k0 < K; k0 += 32) {
    gl2lds16(ga,        lA0);
    gl2lds16(ga + r16K, lA0 + 512);
    gl2lds16(gb,        lB0);
    gl2lds16(gb + r16K, lB0 + 512);
    ga += 32; gb += 32;
    __syncthreads();
    bf16x8 af[4], bg[4];
#pragma unroll
    for (int i = 0; i < 4; i++)
      af[i] = *(const bf16x8*)(As + (wm + i * 16 + tc) * 32 + quad * 8);
#pragma unroll
    for (int j = 0; j < 4; j++)
      bg[j] = *(const bf16x8*)(Bs + (wn + j * 16 + tc) * 32 + quad * 8);
#pragma unroll
    for (int i = 0; i < 4; i++)
#pragma unroll
      for (int j = 0; j < 4; j++)
        acc[i][j] = __builtin_amdgcn_mfma_f32_16x16x32_bf16(af[i], bg[j], acc[i][j], 0, 0, 0);
    __syncthreads();
  }

#pragma unroll
  for (int i = 0; i < 4; i++) {
    const int row0 = bm + wm + i * 16 + quad * 4;
#pragma unroll
    for (int j = 0; j < 4; j++) {
      const int col = bn + wn + j * 16 + tc;
#pragma unroll
      for (int r = 0; r < 4; r++) {
        float v = acc[i][j][r];
        long long idx = (long long)(row0 + r) * N + col;
        if (EPI == 0) {
          u16* C = (u16*)C0v + z * sC;
          C[idx] = f2bf(v + bias[col]);
        } else if (EPI == 1) {
          u16* C = (u16*)C0v + z * sC;
          C[idx] = f2bf(v + bias[row0 + r]);
        } else if (EPI == 2) {
          u16* Ch = (u16*)C0v + z * sC;
          u16* Cl = (u16*)C1v + z * sC;
          u16 h = f2bf(v);
          Ch[idx] = h;
          Cl[idx] = f2bf(v - bf2f(h));
        }
      }
    }
  }
}

// ============================================================
// Fused chaotic kernel (round-4 dataflow): one K-loop, dual accumulators.
//   acc1 = Q.K^T tile, acc2 = Uq.Uk^T tile
//   chaotic = sc + pc*sy + bif*t*(1-t), sc=acc1/32, sy=acc2/512, t=tanh(sc)
// __launch_bounds__(256,2): cap at 256 unified regs -> 2 blocks/CU
// (round 4 measured 284 regs -> 1 block/CU, OccupancyPercent 11%).
// ============================================================
__global__ __launch_bounds__(256, 2)
void chaotic_fused(const u16* __restrict__ Q, const u16* __restrict__ Kt,
                   const u16* __restrict__ Uq, const u16* __restrict__ Uk,
                   float* __restrict__ Cc,
                   float* __restrict__ ssum, float* __restrict__ ssq,
                   const float* __restrict__ bifp, const float* __restrict__ pcp) {
  __shared__ u16 Qs[128 * 32];
  __shared__ u16 Ks[128 * 32];
  __shared__ u16 Us[128 * 32];
  __shared__ u16 Ws[128 * 32];
  const int tid  = threadIdx.x;
  const int wave = tid >> 6;
  const int lane = tid & 63;
  const int quad = lane >> 4;
  const int tc   = lane & 15;
  const int bm = blockIdx.y * 128;
  const int bn = blockIdx.x * 128;
  const long long z = blockIdx.z;
  const long long sQ = (long long)S_LEN * D_MODEL;
  const int wm = (wave & 1) * 64;
  const int wn = (wave >> 1) * 64;

  f32x4 acc1[4][4], acc2[4][4];
#pragma unroll
  for (int i = 0; i < 4; i++)
#pragma unroll
    for (int j = 0; j < 4; j++) {
      acc1[i][j] = (f32x4){0.f, 0.f, 0.f, 0.f};
      acc2[i][j] = (f32x4){0.f, 0.f, 0.f, 0.f};
    }

  const int srow = wave * 32 + (lane >> 2);
  const int scol = (lane & 3) * 8;
  const long long aoff = (long long)(bm + srow) * D_MODEL + scol;
  const long long boff = (long long)(bn + srow) * D_MODEL + scol;
  const u16* gq = Q  + z * sQ + aoff;
  const u16* gk = Kt + z * sQ + boff;
  const u16* gu = Uq + z * sQ + aoff;
  const u16* gw = Uk + z * sQ + boff;
  const int wb = (wave * 32) * 32;
  const long long r16 = 16LL * D_MODEL;

  for (int k0 = 0; k0 < D_MODEL; k0 += 32) {
    gl2lds16(gq,       Qs + wb);
    gl2lds16(gq + r16, Qs + wb + 512);
    gl2lds16(gk,       Ks + wb);
    gl2lds16(gk + r16, Ks + wb + 512);
    gl2lds16(gu,       Us + wb);
    gl2lds16(gu + r16, Us + wb + 512);
    gl2lds16(gw,       Ws + wb);
    gl2lds16(gw + r16, Ws + wb + 512);
    gq += 32; gk += 32; gu += 32; gw += 32;
    __syncthreads();
    {
      bf16x8 af[4], bg[4];
#pragma unroll
      for (int i = 0; i < 4; i++)
        af[i] = *(const bf16x8*)(Qs + (wm + i * 16 + tc) * 32 + quad * 8);
#pragma unroll
      for (int j = 0; j < 4; j++)
        bg[j] = *(const bf16x8*)(Ks + (wn + j * 16 + tc) * 32 + quad * 8);
#pragma unroll
      for (int i = 0; i < 4; i++)
#pragma unroll
        for (int j = 0; j < 4; j++)
          acc1[i][j] = __builtin_amdgcn_mfma_f32_16x16x32_bf16(af[i], bg[j], acc1[i][j], 0, 0, 0);
    }
    {
      bf16x8 cf[4], dg[4];
#pragma unroll
      for (int i = 0; i < 4; i++)
        cf[i] = *(const bf16x8*)(Us + (wm + i * 16 + tc) * 32 + quad * 8);
#pragma unroll
      for (int j = 0; j < 4; j++)
        dg[j] = *(const bf16x8*)(Ws + (wn + j * 16 + tc) * 32 + quad * 8);
#pragma unroll
      for (int i = 0; i < 4; i++)
#pragma unroll
        for (int j = 0; j < 4; j++)
          acc2[i][j] = __builtin_amdgcn_mfma_f32_16x16x32_bf16(cf[i], dg[j], acc2[i][j], 0, 0, 0);
    }
    __syncthreads();
  }

  const float bif = *bifp;
  const float pc  = *pcp;
  float rsum[4][4], rsq[4][4];
#pragma unroll
  for (int i = 0; i < 4; i++)
#pragma unroll
    for (int r = 0; r < 4; r++) { rsum[i][r] = 0.f; rsq[i][r] = 0.f; }

  float* C = Cc + z * (long long)S_LEN * S_LEN;
#pragma unroll
  for (int i = 0; i < 4; i++) {
    const int row0 = bm + wm + i * 16 + quad * 4;
#pragma unroll
    for (int j = 0; j < 4; j++) {
      const int col = bn + wn + j * 16 + tc;
#pragma unroll
      for (int r = 0; r < 4; r++) {
        float sc = acc1[i][j][r] * 0.03125f;          // / sqrt(1024)
        float sy = acc2[i][j][r] * (1.0f / 512.0f);   // / HALF
        float t  = fast_tanh(sc);
        C[(long long)(row0 + r) * S_LEN + col] = sc + pc * sy + bif * t * (1.0f - t);
        rsum[i][r] += sy;
        rsq[i][r]  += sy * sy;
      }
    }
  }
#pragma unroll
  for (int m = 1; m < 16; m <<= 1) {
#pragma unroll
    for (int i = 0; i < 4; i++)
#pragma unroll
      for (int r = 0; r < 4; r++) {
        rsum[i][r] += __shfl_xor(rsum[i][r], m);
        rsq[i][r]  += __shfl_xor(rsq[i][r], m);
      }
  }
  if (tc == 0) {
#pragma unroll
    for (int i = 0; i < 4; i++)
#pragma unroll
      for (int r = 0; r < 4; r++) {
        long long rr = z * S_LEN + bm + wm + i * 16 + quad * 4 + r;
        atomicAdd(&ssum[rr], rsum[i][r]);
        atomicAdd(&ssq[rr],  rsq[i][r]);
      }
  }
}

// ============================================================
// Split-precision output GEMM: out = (Ah+Al)(Bh+Bl)^T + bias, fp32 out.
// 3 MFMAs per frag step (drop Al*Bl). Same tile structure.
// ============================================================
__global__ __launch_bounds__(256)
void mfma_gemm_out3(const u16* __restrict__ Ah, const u16* __restrict__ Al,
                    const u16* __restrict__ Bh, const u16* __restrict__ Bl,
                    const float* __restrict__ bias, float* __restrict__ C,
                    int N, int K) {
  __shared__ u16 Ash[128 * 32];
  __shared__ u16 Asl[128 * 32];
  __shared__ u16 Bsh[128 * 32];
  __shared__ u16 Bsl[128 * 32];
  const int tid  = threadIdx.x;
  const int wave = tid >> 6;
  const int lane = tid & 63;
  const int quad = lane >> 4;
  const int tc   = lane & 15;
  const int bm = blockIdx.y * 128;
  const int bn = blockIdx.x * 128;
  const int wm = (wave & 1) * 64;
  const int wn = (wave >> 1) * 64;

  f32x4 acc[4][4];
#pragma unroll
  for (int i = 0; i < 4; i++)
#pragma unroll
    for (int j = 0; j < 4; j++) acc[i][j] = (f32x4){0.f, 0.f, 0.f, 0.f};

  const int srow = wave * 32 + (lane >> 2);
  const int scol = (lane & 3) * 8;
  long long aoff = (long long)(bm + srow) * K + scol;
  long long boff = (long long)(bn + srow) * K + scol;
  const u16 *gah = Ah + aoff, *gal = Al + aoff;
  const u16 *gbh = Bh + boff, *gbl = Bl + boff;
  const int wbase = (wave * 32) * 32;
  const long long r16K = 16LL * K;

  for (int k0 = 0; k0 < K; k0 += 32) {
    gl2lds16(gah,        Ash + wbase);
    gl2lds16(gah + r16K, Ash + wbase + 512);
    gl2lds16(gal,        Asl + wbase);
    gl2lds16(gal + r16K, Asl + wbase + 512);
    gl2lds16(gbh,        Bsh + wbase);
    gl2lds16(gbh + r16K, Bsh + wbase + 512);
    gl2lds16(gbl,        Bsl + wbase);
    gl2lds16(gbl + r16K, Bsl + wbase + 512);
    gah += 32; gal += 32; gbh += 32; gbl += 32;
    __syncthreads();
    bf16x8 ah[4], al[4], bh[4], bl[4];
#pragma unroll
    for (int i = 0; i < 4; i++) {
      int o = (wm + i * 16 + tc) * 32 + quad * 8;
      ah[i] = *(const bf16x8*)(Ash + o);
      al[i] = *(const bf16x8*)(Asl + o);
    }
#pragma unroll
    for (int j = 0; j < 4; j++) {
      int o = (wn + j * 16 + tc) * 32 + quad * 8;
      bh[j] = *(const bf16x8*)(Bsh + o);
      bl[j] = *(const bf16x8*)(Bsl + o);
    }
#pragma unroll
    for (int i = 0; i < 4; i++)
#pragma unroll
      for (int j = 0; j < 4; j++) {
        acc[i][j] = __builtin_amdgcn_mfma_f32_16x16x32_bf16(ah[i], bh[j], acc[i][j], 0, 0, 0);
        acc[i][j] = __builtin_amdgcn_mfma_f32_16x16x32_bf16(ah[i], bl[j], acc[i][j], 0, 0, 0);
        acc[i][j] = __builtin_amdgcn_mfma_f32_16x16x32_bf16(al[i], bh[j], acc[i][j], 0, 0, 0);
      }
    __syncthreads();
  }
#pragma unroll
  for (int i = 0; i < 4; i++) {
    const int row0 = bm + wm + i * 16 + quad * 4;
#pragma unroll
    for (int j = 0; j < 4; j++) {
      const int col = bn + wn + j * 16 + tc;
#pragma unroll
      for (int r = 0; r < 4; r++)
        C[(long long)(row0 + r) * N + col] = acc[i][j][r] + bias[col];
    }
  }
}

// ============================================================
// Phase normalize in place on dense bf16 pf rows (stride 1024):
// [re|im] -> [re/r | im/r]
// ============================================================
__global__ __launch_bounds__(256)
void phase_norm_bf(u16* __restrict__ U, long long n_rows) {
  long long idx = (long long)blockIdx.x * 256 + threadIdx.x;
  if (idx >= n_rows * N_HALF) return;
  long long row = idx >> 9;
  int j = (int)(idx & (N_HALF - 1));
  u16* p = U + row * D_MODEL;
  float re = bf2f(p[j]), im = bf2f(p[j + N_HALF]);
  float n2 = re * re + im * im;
  float cr = 1.f, sr = 0.f;
  if (n2 > 0.f) {
    float inv = 1.0f / sqrtf(n2);
    cr = re * inv; sr = im * inv;
  }
  p[j] = f2bf(cr); p[j + N_HALF] = f2bf(sr);
}

// ============================================================
// Row softmax: fp32 in (chaotic), bf16 out (attn). 1 block / row.
// ============================================================
__global__ __launch_bounds__(256)
void softmax_bf(const float* __restrict__ Cc, u16* __restrict__ P) {
  const long long row = (long long)blockIdx.y * S_LEN + blockIdx.x;
  const float* p = Cc + row * S_LEN;
  u16* q = P + row * S_LEN;
  const int tid = threadIdx.x;
  float v[8];
  float m = -3.402823466e+38f;
#pragma unroll
  for (int i = 0; i < 8; i++) { v[i] = p[tid + i * 256]; m = fmaxf(m, v[i]); }
#pragma unroll
  for (int mask = 1; mask < 64; mask <<= 1) m = fmaxf(m, __shfl_xor(m, mask));
  __shared__ float red[8];
  if ((tid & 63) == 0) red[tid >> 6] = m;
  __syncthreads();
  m = fmaxf(fmaxf(red[0], red[1]), fmaxf(red[2], red[3]));
  float s = 0.f;
#pragma unroll
  for (int i = 0; i < 8; i++) { v[i] = __expf(v[i] - m); s += v[i]; }
#pragma unroll
  for (int mask = 1; mask < 64; mask <<= 1) s += __shfl_xor(s, mask);
  __syncthreads();
  if ((tid & 63) == 0) red[4 + (tid >> 6)] = s;
  __syncthreads();
  s = red[4] + red[5] + red[6] + red[7];
  float inv = 1.0f / s;
#pragma unroll
  for (int i = 0; i < 8; i++) q[tid + i * 256] = f2bf(v[i] * inv);
}

// ============================================================
// sync_loss
// ============================================================
__global__ __launch_bounds__(1024)
void syncloss_kernel(const float* __restrict__ ssum, const float* __restrict__ ssq,
                     float* __restrict__ out) {
  const int tid = threadIdx.x;
  float acc = 0.f;
  for (int r = tid; r < N_BATCH * S_LEN; r += 1024) {
    float su = ssum[r], sq = ssq[r];
    acc += (sq - su * su * (1.0f / 2048.0f)) * (1.0f / 2047.0f);
  }
#pragma unroll
  for (int mask = 1; mask < 64; mask <<= 1) acc += __shfl_xor(acc, mask);
  __shared__ float red[16];
  if ((tid & 63) == 0) red[tid >> 6] = acc;
  __syncthreads();
  if (tid == 0) {
    float t = 0.f;
#pragma unroll
    for (int k = 0; k < 16; k++) t += red[k];
    out[0] = 0.01f * (t / (float)(N_BATCH * S_LEN));
  }
}

extern "C" void kernel_launch(void* const* d_in, const int* in_sizes, int n_in,
                              void* d_out, int out_size, void* d_ws, size_t ws_size,
                              hipStream_t stream) {
  const float* x    = (const float*)d_in[0];
  const float* Wq   = (const float*)d_in[1];
  const float* bq   = (const float*)d_in[2];
  const float* Wk   = (const float*)d_in[3];
  const float* bk   = (const float*)d_in[4];
  const float* Wv   = (const float*)d_in[5];
  const float* bv   = (const float*)d_in[6];
  const float* Wp   = (const float*)d_in[7];
  const float* bp   = (const float*)d_in[8];
  const float* Wo   = (const float*)d_in[9];
  const float* bo   = (const float*)d_in[10];
  const float* bifp = (const float*)d_in[11];
  const float* pcp  = (const float*)d_in[12];
  float* out = (float*)d_out;

  const long long NROW = (long long)N_BATCH * S_LEN;   // 8192
  const long long TD   = NROW * D_MODEL;               // 8,388,608
  const long long WSZ  = (long long)D_MODEL * D_MODEL; // 1,048,576

  // workspace layout (~180 MB) — identical to round 4
  u16* xbf  = (u16*)d_ws;           // TD
  u16* wqkb = xbf + TD;             // 2*WSZ (Wq then Wk, contiguous)
  u16* wvb  = wqkb + 2 * WSZ;
  u16* wpb  = wvb + WSZ;
  u16* woh  = wpb + WSZ;
  u16* wol  = woh + WSZ;
  u16* Qbf  = wol + WSZ;            // TD
  u16* Kbf  = Qbf + TD;             // TD (contiguous with Qbf)
  u16* pfQ  = Kbf + TD;             // TD  (-> Uq, later av_hi)
  u16* pfK  = pfQ + TD;             // TD  (-> Uk, later av_lo; contiguous with pfQ)
  u16* Vt   = pfK + TD;             // TD  ([b][d][s])
  float* Cc = (float*)(Vt + TD);    // B*S*S fp32
  float* ssum = Cc + (long long)N_BATCH * S_LEN * S_LEN;
  float* ssq  = ssum + NROW;
  u16* attn = Qbf;                  // overlays Q+K after chaotic (2*TD u16)
  u16* avh  = pfQ;                  // overlays Uq after av
  u16* avl  = pfK;

  dim3 blk(256);
  const long long sQ = (long long)S_LEN * D_MODEL;   // 2048*1024
  const long long sS = (long long)S_LEN * S_LEN;

  // casts
  cast_bf<<<(int)(TD / 256), blk, 0, stream>>>(x, xbf, TD);
  cast_bf<<<(int)(WSZ / 256), blk, 0, stream>>>(Wq, wqkb, WSZ);
  cast_bf<<<(int)(WSZ / 256), blk, 0, stream>>>(Wk, wqkb + WSZ, WSZ);
  cast_bf<<<(int)(WSZ / 256), blk, 0, stream>>>(Wv, wvb, WSZ);
  cast_bf<<<(int)(WSZ / 256), blk, 0, stream>>>(Wp, wpb, WSZ);
  cast_split<<<(int)(WSZ / 256), blk, 0, stream>>>(Wo, woh, wol, WSZ);

  // Q -> Qbf, K -> Kbf (dense; z selects {Wq,bq}/{Wk,bk}; per-block math
  // identical to two separate round-4 launches — biases are zeros anyway)
  mfma_gemm<0><<<dim3(8, 64, 2), blk, 0, stream>>>(
      xbf, wqkb, bq, bk, Qbf, nullptr,
      D_MODEL, D_MODEL, 0, WSZ, TD);
  // Vt[b][d][s] = Wv@x_b^T + bv[d]  (row bias)
  mfma_gemm<1><<<dim3(16, 8, N_BATCH), blk, 0, stream>>>(
      wvb, xbf, bv, nullptr, Vt, nullptr,
      S_LEN, D_MODEL, 0, sQ, (long long)D_MODEL * S_LEN);
  // pf = [Q;K]@Wp^T + bp  (single launch over 16384 contiguous rows)
  mfma_gemm<0><<<dim3(8, 128, 1), blk, 0, stream>>>(
      Qbf, wpb, bp, nullptr, pfQ, nullptr,
      D_MODEL, D_MODEL, 0, 0, 0);
  phase_norm_bf<<<(int)(2 * NROW * N_HALF / 256), blk, 0, stream>>>(pfQ, 2 * NROW);
  zero_stats<<<(int)((2 * NROW + 255) / 256), blk, 0, stream>>>(ssum, (int)(2 * NROW));

  // fused: scores + sync + chaotic -> Cc (fp32), + row stats
  chaotic_fused<<<dim3(16, 16, N_BATCH), blk, 0, stream>>>(
      Qbf, Kbf, pfQ, pfK, Cc, ssum, ssq, bifp, pcp);
  // softmax (fp32 in, bf16 attn out; overlays Q/K)
  softmax_bf<<<dim3(S_LEN, N_BATCH), blk, 0, stream>>>(Cc, attn);
  // av = attn @ Vt^T  -> hi/lo bf16 (overlays Uq/Uk)
  mfma_gemm<2><<<dim3(8, 16, N_BATCH), blk, 0, stream>>>(
      attn, Vt, nullptr, nullptr, avh, avl,
      D_MODEL, S_LEN, sS, (long long)D_MODEL * S_LEN, sQ);
  // out = (avh+avl)@(Woh+Wol)^T + bo   (fp32, split 3-MFMA)
  mfma_gemm_out3<<<dim3(8, 64, 1), blk, 0, stream>>>(avh, avl, woh, wol, bo, out,
      D_MODEL, D_MODEL);
  // sync_loss
  syncloss_kernel<<<1, 1024, 0, stream>>>(ssum, ssq, out + TD);
}